// Round 21
// baseline (323.895 us; speedup 1.0000x reference)
//
#include <hip/hip_runtime.h>
#include <hip/hip_cooperative_groups.h>

namespace cg = cooperative_groups;

// KNN argmin over L2, round 21: cooperative mega-kernel, launch-robust.
// R20's coop launch was rejected (all-zero out, fast return => launch error,
// not deadlock/data-bug): hard-coded 1024 blocks = exactly 4/CU with zero
// margin -> hipErrorCooperativeLaunchTooLarge if runtime occupancy says 3.
// R21: (a) grid-stride unit loops (any grid correct); (b) grid sized from
// hipOccupancyMaxActiveBlocksPerMultiprocessor (API contract: coop launch
// of <= maxB*numCU blocks is legal); (c) deterministic host-side guards
// (occupancy + hipDeviceAttributeCooperativeLaunch) route to the R19-proven
// 3-dispatch path instead of risking a failed launch during capture.
// Phase bodies are R19's text verbatim (proven 153.3us as 3 dispatches).
//
// Filter certification (R19, self-contained): c = 2^-9*1.01 <= 0.002;
// phaseA C-init = -0.499*|s|^2 folds the AM-GM |s|^2 term, so rescoring
// blocks with bmin <= min + 0.004*|q|^2 + 0.05 provably contains the true
// first argmin. Phase B exact fp32 keys, strict-< ascending scan +
// lexicographic cross-lane reduce => np.argmin first-index semantics.

#define NTOT   16384
#define DIM    64
#define EPS_COEF 0.004f
#define EPS_ABS  0.05f
#define CINIT_COEF (-0.499f)
#define FLT_BIG 3.4e38f

typedef __attribute__((ext_vector_type(8))) short short8;
typedef __attribute__((ext_vector_type(4))) float float4v;

__device__ __forceinline__ ushort f16_bits(float x) {
  union { _Float16 f; ushort u; } c;
  c.f = (_Float16)x;  // v_cvt_f16_f32, RNE
  return c.u;
}

__device__ __forceinline__ void pin8(short8& v) {
  asm volatile("" : "+v"(v));
}

// ===========================================================================
// Phase bodies (R19 text, blockIdx replaced by a unit parameter).
// ===========================================================================

__device__ __forceinline__ void prep_body(
    int vb, const float* __restrict__ S, const float* __restrict__ Q,
    ushort* __restrict__ Sh, ushort* __restrict__ Qh,
    float* __restrict__ sqS, float* __restrict__ sqQ,
    float* __restrict__ S_T, float (*tile)[65]) {
  const int tid = threadIdx.x;
  const bool isS = vb < 256;
  const int rbase = (vb & 255) * 64;
  const float* __restrict__ src = isS ? S : Q;
  ushort* __restrict__ dh = isS ? Sh : Qh;

  const int tx = tid & 63;
  const int ty = tid >> 6;
#pragma unroll
  for (int i = 0; i < 16; ++i) {
    const int r = i * 4 + ty;
    tile[r][tx] = src[(size_t)(rbase + r) * DIM + tx];  // coalesced
  }
  __syncthreads();

  if (isS) {  // transposed copy (coalesced, pad-safe)
#pragma unroll
    for (int i = 0; i < 16; ++i) {
      const int d = i * 4 + ty;
      S_T[(size_t)d * NTOT + rbase + tx] = tile[tx][d];
    }
  }

  const int panel = tid >> 6;
  const int half = (tid >> 5) & 1;
  const int slot0 = (tid & 31) * 2;
#pragma unroll
  for (int ss = 0; ss < 2; ++ss) {
    const int s = slot0 + ss;
    const int m = s & 15;
    const int q8 = s >> 4;
    const int row = panel * 16 + m;
    const int kb = half * 32 + q8 * 8;
    short8 hv;
#pragma unroll
    for (int j = 0; j < 8; ++j) hv[j] = (short)f16_bits(tile[row][kb + j]);
    const size_t goff =
        (size_t)((rbase >> 4) + panel) * 1024 + (size_t)half * 512 + (size_t)s * 8;
    *(short8*)&dh[goff] = hv;
  }

  if (tid < 64) {
    float acc = 0.0f;
#pragma unroll
    for (int d = 0; d < DIM; ++d) {
      const float v = tile[tid][d];
      acc = fmaf(v, v, acc);
    }
    (isS ? sqS : sqQ)[rbase + tid] = acc;
  }
  __syncthreads();  // tile safe for next grid-stride iteration
}

#define MFMA16F(A, B, C) __builtin_amdgcn_mfma_f32_16x16x32_f16(A, B, C, 0, 0, 0)

#define STEP_COMPUTE(H0, H1, SQ)                                           \
  do {                                                                     \
    float4v cinit;                                                         \
    cinit[0] = CINIT_COEF * SQ.x;                                          \
    cinit[1] = CINIT_COEF * SQ.y;                                          \
    cinit[2] = CINIT_COEF * SQ.z;                                          \
    cinit[3] = CINIT_COEF * SQ.w;                                          \
    _Pragma("unroll")                                                      \
    for (int t = 0; t < 4; ++t) {                                          \
      float4v a = MFMA16F(H0, qh[t][0], cinit);                            \
      a = MFMA16F(H1, qh[t][1], a);                                        \
      bmr[t] = fmaxf(bmr[t], fmaxf(fmaxf(a[0], a[1]), fmaxf(a[2], a[3]))); \
    }                                                                      \
  } while (0)

template <int BST>
__device__ __forceinline__ void phaseA_body(
    int split, int qbase, const ushort* __restrict__ Sh,
    const ushort* __restrict__ Qh, const float* __restrict__ sqS,
    float* __restrict__ bmin) {
  constexpr int NSB = NTOT / (16 * BST);
  const int tid = threadIdx.x;
  const int l = tid & 63;
  const int w = tid >> 6;
  const int lm = l & 15;
  const int lq = l >> 4;
  const int sbase = split * 2048 + w * 512;

  short8 qh[4][2];
#pragma unroll
  for (int t = 0; t < 4; ++t) {
    const size_t pb = (size_t)((qbase >> 4) + t) * 1024 + (size_t)l * 8;
    qh[t][0] = *(const short8*)&Qh[pb];
    qh[t][1] = *(const short8*)&Qh[pb + 512];
  }
#pragma unroll
  for (int t = 0; t < 4; ++t) {
    pin8(qh[t][0]);
    pin8(qh[t][1]);
  }

  const ushort* pSh = Sh + (size_t)(sbase >> 4) * 1024 + (size_t)l * 8;
  const float* psq = sqS + sbase + lq * 4;

  short8 h0a = *(const short8*)(pSh);
  short8 h1a = *(const short8*)(pSh + 512);
  float4 sqa = *(const float4*)(psq);
  short8 h0b = *(const short8*)(pSh + 1024);
  short8 h1b = *(const short8*)(pSh + 1024 + 512);
  float4 sqb = *(const float4*)(psq + 16);

  float bmr[4] = {-FLT_BIG, -FLT_BIG, -FLT_BIG, -FLT_BIG};

  for (int st = 0; st < 32; st += 2) {
    STEP_COMPUTE(h0a, h1a, sqa);
    if (st + 2 < 32) {
      const int off = (st + 2) * 1024;
      h0a = *(const short8*)(pSh + off);
      h1a = *(const short8*)(pSh + off + 512);
      sqa = *(const float4*)(psq + (st + 2) * 16);
    }
    STEP_COMPUTE(h0b, h1b, sqb);
    if (st + 3 < 32) {
      const int off = (st + 3) * 1024;
      h0b = *(const short8*)(pSh + off);
      h1b = *(const short8*)(pSh + off + 512);
      sqb = *(const float4*)(psq + (st + 3) * 16);
    }
    if (((st + 1) & (BST - 1)) == (BST - 1)) {
      const int gb = split * (128 / BST) + w * (32 / BST) + ((st + 1) / BST);
#pragma unroll
      for (int t = 0; t < 4; ++t) {
        float v = bmr[t];
        v = fmaxf(v, __shfl_xor(v, 16, 64));
        v = fmaxf(v, __shfl_xor(v, 32, 64));
        if (lq == 0) bmin[(size_t)(qbase + t * 16 + lm) * NSB + gb] = -2.0f * v;
        bmr[t] = -FLT_BIG;
      }
    }
  }
}

template <int SBLK>
__device__ __forceinline__ void phaseB_body(
    int u, const float* __restrict__ S_T, const float* __restrict__ Q,
    const float* __restrict__ sqS, const float* __restrict__ sqQ,
    const float* __restrict__ bmin, const float* __restrict__ onehot,
    float* __restrict__ out, float (*sQrow)[64]) {
  constexpr int NSB = NTOT / SBLK;
  constexpr int NB64 = NSB / 64;
  constexpr int SPL = SBLK / 64;

  const int lane = threadIdx.x & 63;
  const int w = threadIdx.x >> 6;
  const int q = u * 4 + w;

  if (lane < 16)
    *(float4*)&sQrow[w][lane * 4] = *(const float4*)&Q[(size_t)q * DIM + lane * 4];
  __syncthreads();

  const float eps = EPS_COEF * sqQ[q] + EPS_ABS;

  float bv[NB64];
#pragma unroll
  for (int j = 0; j < NB64; ++j) bv[j] = bmin[(size_t)q * NSB + j * 64 + lane];
  float m = bv[0];
#pragma unroll
  for (int j = 1; j < NB64; ++j) m = fminf(m, bv[j]);
#pragma unroll
  for (int d = 1; d < 64; d <<= 1) m = fminf(m, __shfl_xor(m, d, 64));
  const float thr = m + eps;

  float bk = FLT_BIG;
  int bi = 0;
#pragma unroll
  for (int j = 0; j < NB64; ++j) {
    unsigned long long msk = __ballot(bv[j] <= thr);
    while (msk) {  // ascending block order; wave-uniform control
      const int b = j * 64 + (__ffsll((long long)msk) - 1);
      msk &= msk - 1;
      const int s0 = b * SBLK + lane * SPL;
      if (SPL == 2) {
        float a0 = 0.f, a1 = 0.f;
#pragma unroll
        for (int c = 0; c < 16; ++c) {
          const float4 qv = *(const float4*)&sQrow[w][c * 4];
          const float2 x0 = *(const float2*)&S_T[(size_t)(c * 4 + 0) * NTOT + s0];
          const float2 x1 = *(const float2*)&S_T[(size_t)(c * 4 + 1) * NTOT + s0];
          const float2 x2 = *(const float2*)&S_T[(size_t)(c * 4 + 2) * NTOT + s0];
          const float2 x3 = *(const float2*)&S_T[(size_t)(c * 4 + 3) * NTOT + s0];
          a0 = fmaf(qv.x, x0.x, a0); a1 = fmaf(qv.x, x0.y, a1);
          a0 = fmaf(qv.y, x1.x, a0); a1 = fmaf(qv.y, x1.y, a1);
          a0 = fmaf(qv.z, x2.x, a0); a1 = fmaf(qv.z, x2.y, a1);
          a0 = fmaf(qv.w, x3.x, a0); a1 = fmaf(qv.w, x3.y, a1);
        }
        const float2 sq2 = *(const float2*)&sqS[s0];
        const float k0 = fmaf(-2.f, a0, sq2.x);
        const float k1 = fmaf(-2.f, a1, sq2.y);
        bool uu;  // ascending index, strict < => first minimum per lane
        uu = k0 < bk; bk = uu ? k0 : bk; bi = uu ? s0 : bi;
        uu = k1 < bk; bk = uu ? k1 : bk; bi = uu ? (s0 + 1) : bi;
      } else {
        float a0 = 0.f, a1 = 0.f, a2 = 0.f, a3 = 0.f;
#pragma unroll
        for (int c = 0; c < 16; ++c) {
          const float4 qv = *(const float4*)&sQrow[w][c * 4];
          const float4 s0v = *(const float4*)&S_T[(size_t)(c * 4 + 0) * NTOT + s0];
          const float4 s1v = *(const float4*)&S_T[(size_t)(c * 4 + 1) * NTOT + s0];
          const float4 s2v = *(const float4*)&S_T[(size_t)(c * 4 + 2) * NTOT + s0];
          const float4 s3v = *(const float4*)&S_T[(size_t)(c * 4 + 3) * NTOT + s0];
          a0 = fmaf(qv.x, s0v.x, a0); a1 = fmaf(qv.x, s0v.y, a1);
          a2 = fmaf(qv.x, s0v.z, a2); a3 = fmaf(qv.x, s0v.w, a3);
          a0 = fmaf(qv.y, s1v.x, a0); a1 = fmaf(qv.y, s1v.y, a1);
          a2 = fmaf(qv.y, s1v.z, a2); a3 = fmaf(qv.y, s1v.w, a3);
          a0 = fmaf(qv.z, s2v.x, a0); a1 = fmaf(qv.z, s2v.y, a1);
          a2 = fmaf(qv.z, s2v.z, a2); a3 = fmaf(qv.z, s2v.w, a3);
          a0 = fmaf(qv.w, s3v.x, a0); a1 = fmaf(qv.w, s3v.y, a1);
          a2 = fmaf(qv.w, s3v.z, a2); a3 = fmaf(qv.w, s3v.w, a3);
        }
        const float4 sq4 = *(const float4*)&sqS[s0];
        const float k0 = fmaf(-2.f, a0, sq4.x);
        const float k1 = fmaf(-2.f, a1, sq4.y);
        const float k2 = fmaf(-2.f, a2, sq4.z);
        const float k3 = fmaf(-2.f, a3, sq4.w);
        bool uu;
        uu = k0 < bk; bk = uu ? k0 : bk; bi = uu ? s0 : bi;
        uu = k1 < bk; bk = uu ? k1 : bk; bi = uu ? (s0 + 1) : bi;
        uu = k2 < bk; bk = uu ? k2 : bk; bi = uu ? (s0 + 2) : bi;
        uu = k3 < bk; bk = uu ? k3 : bk; bi = uu ? (s0 + 3) : bi;
      }
    }
  }
#pragma unroll
  for (int d = 1; d < 64; d <<= 1) {
    const float ok = __shfl_xor(bk, d, 64);
    const int oi = __shfl_xor(bi, d, 64);
    const bool uu = (ok < bk) || (ok == bk && oi < bi);
    bk = uu ? ok : bk;
    bi = uu ? oi : bi;
  }
  const float ov = onehot[(size_t)bi * 64 + lane];
  const unsigned long long lmask = __ballot(ov > 0.5f);
  const int label = __ffsll((long long)lmask) - 1;
  out[(size_t)q * 64 + lane] = (lane == label) ? 1.0f : 0.0f;
  __syncthreads();  // sQrow safe for next grid-stride iteration
}

// ===========================================================================
// Mega-kernel: grid-stride units, two grid syncs. Works at ANY grid size.
// ===========================================================================
__global__ __launch_bounds__(256, 4) void k_mega(
    const float* __restrict__ S, const float* __restrict__ Q,
    const float* __restrict__ OH, float* __restrict__ out,
    ushort* __restrict__ Sh, ushort* __restrict__ Qh,
    float* __restrict__ sqS, float* __restrict__ sqQ,
    float* __restrict__ S_T, float* __restrict__ bmin) {
  __shared__ float tile[64][65];   // prep staging (16.6 KB)
  __shared__ float sQrow[4][64];   // phaseB query rows (1 KB)
  cg::grid_group grid = cg::this_grid();
  const int nb = gridDim.x;

  for (int u = blockIdx.x; u < 512; u += nb)
    prep_body(u, S, Q, Sh, Qh, sqS, sqQ, S_T, tile);
  grid.sync();

  for (int u = blockIdx.x; u < 2048; u += nb)
    phaseA_body<8>(u & 7, (u >> 3) * 64, Sh, Qh, sqS, bmin);
  grid.sync();

  for (int u = blockIdx.x; u < 4096; u += nb)
    phaseB_body<128>(u, S_T, Q, sqS, sqQ, bmin, OH, out, sQrow);
}

// ===========================================================================
// Fallback: R19's proven 3-dispatch pipeline (128-granular when ws allows).
// ===========================================================================
__global__ __launch_bounds__(256) void k_prep_fb(
    const float* __restrict__ S, const float* __restrict__ Q,
    ushort* __restrict__ Sh, ushort* __restrict__ Qh,
    float* __restrict__ sqS, float* __restrict__ sqQ,
    float* __restrict__ S_T) {
  __shared__ float tile[64][65];
  prep_body(blockIdx.x, S, Q, Sh, Qh, sqS, sqQ, S_T, tile);
}

template <int BST>
__global__ __launch_bounds__(256, 3) void k_phaseA_fb(
    const ushort* __restrict__ Sh, const ushort* __restrict__ Qh,
    const float* __restrict__ sqS, float* __restrict__ bmin) {
  phaseA_body<BST>(blockIdx.x, blockIdx.y * 64, Sh, Qh, sqS, bmin);
}

template <int SBLK>
__global__ __launch_bounds__(256) void k_phaseB_fb(
    const float* __restrict__ S_T, const float* __restrict__ Q,
    const float* __restrict__ sqS, const float* __restrict__ sqQ,
    const float* __restrict__ bmin, const float* __restrict__ onehot,
    float* __restrict__ out) {
  __shared__ float sQrow[4][64];
  phaseB_body<SBLK>(blockIdx.x, S_T, Q, sqS, sqQ, bmin, onehot, out, sQrow);
}

// ---------------------------------------------------------------------------
extern "C" void kernel_launch(void* const* d_in, const int* in_sizes, int n_in,
                              void* d_out, int out_size, void* d_ws, size_t ws_size,
                              hipStream_t stream) {
  const float* S = (const float*)d_in[0];   // [16384][64]
  const float* Q = (const float*)d_in[1];   // [16384][64]
  const float* OH = (const float*)d_in[2];  // [16384][64]
  float* out = (float*)d_out;

  char* ws = (char*)d_ws;
  ushort* Sh = (ushort*)ws;                                  // [0, 2MB)
  ushort* Qh = (ushort*)(ws + (2u << 20));                   // [2, 4MB)
  float* S_T = (float*)(ws + (4u << 20));                    // [4, 8MB)
  float* sqS = (float*)(ws + (8u << 20));                    // 64 KB
  float* sqQ = (float*)(ws + (8u << 20) + (64u << 10));      // 64 KB
  float* bmin = (float*)(ws + (8u << 20) + (128u << 10));    // up to 8 MB

  const bool bigWs = ws_size >= (17u << 20);

  // Deterministic, capture-safe host-side guards (no failed launches).
  bool useCoop = false;
  int gridBlocks = 0;
  if (bigWs) {
    int dev = 0, coopAttr = 0, maxB = 0;
    if (hipGetDevice(&dev) == hipSuccess &&
        hipDeviceGetAttribute(&coopAttr, hipDeviceAttributeCooperativeLaunch,
                              dev) == hipSuccess &&
        coopAttr != 0 &&
        hipOccupancyMaxActiveBlocksPerMultiprocessor(
            &maxB, (const void*)k_mega, 256, 0) == hipSuccess &&
        maxB >= 1) {
      gridBlocks = maxB * 256;           // 256 CUs on MI355X
      if (gridBlocks > 1024) gridBlocks = 1024;
      useCoop = true;
    }
  }

  if (useCoop) {
    const float* a0 = S; const float* a1 = Q; const float* a2 = OH;
    float* a3 = out; ushort* a4 = Sh; ushort* a5 = Qh;
    float* a6 = sqS; float* a7 = sqQ; float* a8 = S_T; float* a9 = bmin;
    void* args[] = {&a0, &a1, &a2, &a3, &a4, &a5, &a6, &a7, &a8, &a9};
    hipLaunchCooperativeKernel((void*)k_mega, dim3(gridBlocks), dim3(256),
                               args, 0, stream);
  } else if (bigWs) {
    k_prep_fb<<<dim3(512), 256, 0, stream>>>(S, Q, Sh, Qh, sqS, sqQ, S_T);
    k_phaseA_fb<8><<<dim3(8, NTOT / 64), 256, 0, stream>>>(Sh, Qh, sqS, bmin);
    k_phaseB_fb<128><<<dim3(NTOT / 4), 256, 0, stream>>>(S_T, Q, sqS, sqQ,
                                                         bmin, OH, out);
  } else {
    k_prep_fb<<<dim3(512), 256, 0, stream>>>(S, Q, Sh, Qh, sqS, sqQ, S_T);
    k_phaseA_fb<16><<<dim3(8, NTOT / 64), 256, 0, stream>>>(Sh, Qh, sqS, bmin);
    k_phaseB_fb<256><<<dim3(NTOT / 4), 256, 0, stream>>>(S_T, Q, sqS, sqQ,
                                                         bmin, OH, out);
  }
  (void)in_sizes; (void)n_in; (void)out_size; (void)ws_size;
}

// Round 22
// 154.212 us; speedup vs baseline: 2.1003x; 2.1003x over previous
//
#include <hip/hip_runtime.h>

// KNN argmin over L2, round 22: R19 (proven best, 153.3us) with ONE diff:
// k_phaseA __launch_bounds__(256,3) -> (256,4). phaseA's live set is ~60
// arch-VGPRs + 32 pinned frag regs in AGPRs (~92 total) < the 128 cap, and
// occupancy was ~26% (2 blocks/CU); 4 blocks/CU doubles latency cover for
// the MFMA/load chain. grid 2048 = exactly 2 residency rounds.
// R20/R21 verdict: cooperative fusion abandoned (grid-stride+grid.sync
// structure cost >> the ~38us boundary saving; 365us measured).
//
// Filter certification (R19, self-contained): c = 2^-9*1.01 <= 0.002;
// phaseA C-init = -0.499*|s|^2 folds the AM-GM |s|^2 term, so rescoring
// blocks with bmin <= min + 0.004*|q|^2 + 0.05 provably contains the true
// first argmin. Phase B exact fp32 keys, strict-< ascending scan +
// lexicographic cross-lane reduce => np.argmin first-index semantics.

#define NTOT   16384
#define DIM    64
#define EPS_COEF 0.004f   // 2c with c=0.002 (>= 2^-9*1.01)
#define EPS_ABS  0.05f
#define CINIT_COEF (-0.499f)  // -(1-c)/2
#define FLT_BIG 3.4e38f

typedef __attribute__((ext_vector_type(8))) short short8;
typedef __attribute__((ext_vector_type(4))) float float4v;

__device__ __forceinline__ ushort f16_bits(float x) {
  union { _Float16 f; ushort u; } c;
  c.f = (_Float16)x;  // v_cvt_f16_f32, RNE
  return c.u;
}

// Opaque def: forbids rematerialization (forces register residency).
__device__ __forceinline__ void pin8(short8& v) {
  asm volatile("" : "+v"(v));
}

// ---------------------------------------------------------------------------
// Fused prep: blocks 0..255 -> S (f16 panels + sqS + S_T);
// blocks 256..511 -> Q (f16 panels + sqQ). Panel layout (R8-proven):
//   off(r,k) = (r>>4)*1024 + (k>>5)*512 + (((k&31)>>3)*16 + (r&15))*8 + (k&7)
__global__ __launch_bounds__(256) void k_prep(
    const float* __restrict__ S, const float* __restrict__ Q,
    ushort* __restrict__ Sh, ushort* __restrict__ Qh,
    float* __restrict__ sqS, float* __restrict__ sqQ,
    float* __restrict__ S_T) {
  __shared__ float tile[64][65];
  const int tid = threadIdx.x;
  const bool isS = blockIdx.x < 256;
  const int rbase = (blockIdx.x & 255) * 64;
  const float* __restrict__ src = isS ? S : Q;
  ushort* __restrict__ dh = isS ? Sh : Qh;

  const int tx = tid & 63;
  const int ty = tid >> 6;
#pragma unroll
  for (int i = 0; i < 16; ++i) {
    const int r = i * 4 + ty;
    tile[r][tx] = src[(size_t)(rbase + r) * DIM + tx];  // coalesced
  }
  __syncthreads();

  if (isS) {  // transposed copy (coalesced, pad-safe)
#pragma unroll
    for (int i = 0; i < 16; ++i) {
      const int d = i * 4 + ty;
      S_T[(size_t)d * NTOT + rbase + tx] = tile[tx][d];
    }
  }

  // Panel-swizzled f16; stores are lane-contiguous 16B.
  const int panel = tid >> 6;           // 0..3
  const int half = (tid >> 5) & 1;      // k-half
  const int slot0 = (tid & 31) * 2;     // slot = q8*16 + m
#pragma unroll
  for (int ss = 0; ss < 2; ++ss) {
    const int s = slot0 + ss;
    const int m = s & 15;
    const int q8 = s >> 4;
    const int row = panel * 16 + m;
    const int kb = half * 32 + q8 * 8;
    short8 hv;
#pragma unroll
    for (int j = 0; j < 8; ++j) hv[j] = (short)f16_bits(tile[row][kb + j]);
    const size_t goff =
        (size_t)((rbase >> 4) + panel) * 1024 + (size_t)half * 512 + (size_t)s * 8;
    *(short8*)&dh[goff] = hv;
  }

  // Row sum of squares.
  if (tid < 64) {
    float acc = 0.0f;
#pragma unroll
    for (int d = 0; d < DIM; ++d) {
      const float v = tile[tid][d];
      acc = fmaf(v, v, acc);
    }
    (isS ? sqS : sqQ)[rbase + tid] = acc;
  }
}

// ---------------------------------------------------------------------------
// Phase A: block = 4 waves; wave w: 64 queries x 512 supports.
// grid = (8 splits, 256 q-tiles). 16x16x32 f16 MFMA (fragment layout as the
// R4-R19 HW-verified family). C init -0.499*sq (error-absorbing); 2-MFMA
// chain per tile; fold block-max of a => bmin = -2*max = blockmin key_L.

#define MFMA16F(A, B, C) __builtin_amdgcn_mfma_f32_16x16x32_f16(A, B, C, 0, 0, 0)

#define STEP_COMPUTE(H0, H1, SQ)                                           \
  do {                                                                     \
    float4v cinit;                                                         \
    cinit[0] = CINIT_COEF * SQ.x;                                          \
    cinit[1] = CINIT_COEF * SQ.y;                                          \
    cinit[2] = CINIT_COEF * SQ.z;                                          \
    cinit[3] = CINIT_COEF * SQ.w;                                          \
    _Pragma("unroll")                                                      \
    for (int t = 0; t < 4; ++t) {                                          \
      float4v a = MFMA16F(H0, qh[t][0], cinit);                            \
      a = MFMA16F(H1, qh[t][1], a);                                        \
      bmr[t] = fmaxf(bmr[t], fmaxf(fmaxf(a[0], a[1]), fmaxf(a[2], a[3]))); \
    }                                                                      \
  } while (0)

template <int BST>  // steps per bmin block (8 -> 128-support granularity)
__global__ __launch_bounds__(256, 4) void k_phaseA(
    const ushort* __restrict__ Sh, const ushort* __restrict__ Qh,
    const float* __restrict__ sqS, float* __restrict__ bmin) {
  constexpr int NSB = NTOT / (16 * BST);
  const int tid = threadIdx.x;
  const int l = tid & 63;
  const int w = tid >> 6;
  const int lm = l & 15;
  const int lq = l >> 4;
  const int split = blockIdx.x;       // 0..7
  const int qbase = blockIdx.y * 64;
  const int sbase = split * 2048 + w * 512;

  // Query (B) fragments: 4 tiles x 2 k-chunks, pinned (resident in AGPRs).
  short8 qh[4][2];
#pragma unroll
  for (int t = 0; t < 4; ++t) {
    const size_t pb = (size_t)((qbase >> 4) + t) * 1024 + (size_t)l * 8;
    qh[t][0] = *(const short8*)&Qh[pb];
    qh[t][1] = *(const short8*)&Qh[pb + 512];
  }
#pragma unroll
  for (int t = 0; t < 4; ++t) {
    pin8(qh[t][0]);
    pin8(qh[t][1]);
  }

  const ushort* pSh = Sh + (size_t)(sbase >> 4) * 1024 + (size_t)l * 8;
  const float* psq = sqS + sbase + lq * 4;

  // Copy-free double buffer: even steps use (a), odd steps use (b).
  short8 h0a = *(const short8*)(pSh);
  short8 h1a = *(const short8*)(pSh + 512);
  float4 sqa = *(const float4*)(psq);
  short8 h0b = *(const short8*)(pSh + 1024);
  short8 h1b = *(const short8*)(pSh + 1024 + 512);
  float4 sqb = *(const float4*)(psq + 16);

  float bmr[4] = {-FLT_BIG, -FLT_BIG, -FLT_BIG, -FLT_BIG};

  for (int st = 0; st < 32; st += 2) {
    STEP_COMPUTE(h0a, h1a, sqa);
    if (st + 2 < 32) {
      const int off = (st + 2) * 1024;
      h0a = *(const short8*)(pSh + off);
      h1a = *(const short8*)(pSh + off + 512);
      sqa = *(const float4*)(psq + (st + 2) * 16);
    }
    STEP_COMPUTE(h0b, h1b, sqb);
    if (st + 3 < 32) {
      const int off = (st + 3) * 1024;
      h0b = *(const short8*)(pSh + off);
      h1b = *(const short8*)(pSh + off + 512);
      sqb = *(const float4*)(psq + (st + 3) * 16);
    }
    if (((st + 1) & (BST - 1)) == (BST - 1)) {  // finished a bmin block
      const int gb = split * (128 / BST) + w * (32 / BST) + ((st + 1) / BST);
#pragma unroll
      for (int t = 0; t < 4; ++t) {
        float v = bmr[t];
        v = fmaxf(v, __shfl_xor(v, 16, 64));
        v = fmaxf(v, __shfl_xor(v, 32, 64));
        if (lq == 0) bmin[(size_t)(qbase + t * 16 + lm) * NSB + gb] = -2.0f * v;
        bmr[t] = -FLT_BIG;
      }
    }
  }
}

// ---------------------------------------------------------------------------
// Phase B: one wave per query; serial coalesced rescore from S_T
// (R16/R19-proven structure). eps = 0.004*|q|^2 + 0.05.
template <int SBLK>
__global__ __launch_bounds__(256) void k_phaseB(
    const float* __restrict__ S_T,   // [64][NTOT]
    const float* __restrict__ Q,     // [NTOT][64]
    const float* __restrict__ sqS, const float* __restrict__ sqQ,
    const float* __restrict__ bmin,
    const float* __restrict__ onehot, float* __restrict__ out) {
  constexpr int NSB = NTOT / SBLK;    // 128 or 64
  constexpr int NB64 = NSB / 64;
  constexpr int SPL = SBLK / 64;      // supports per lane: 2 or 4

  __shared__ float sQrow[4][64];
  const int lane = threadIdx.x & 63;
  const int w = threadIdx.x >> 6;
  const int q = blockIdx.x * 4 + w;

  if (lane < 16)
    *(float4*)&sQrow[w][lane * 4] = *(const float4*)&Q[(size_t)q * DIM + lane * 4];
  __syncthreads();

  // Per-query certified filter width (no global data needed).
  const float eps = EPS_COEF * sqQ[q] + EPS_ABS;

  float bv[NB64];
#pragma unroll
  for (int j = 0; j < NB64; ++j) bv[j] = bmin[(size_t)q * NSB + j * 64 + lane];
  float m = bv[0];
#pragma unroll
  for (int j = 1; j < NB64; ++j) m = fminf(m, bv[j]);
#pragma unroll
  for (int d = 1; d < 64; d <<= 1) m = fminf(m, __shfl_xor(m, d, 64));
  const float thr = m + eps;

  float bk = FLT_BIG;
  int bi = 0;
#pragma unroll
  for (int j = 0; j < NB64; ++j) {
    unsigned long long msk = __ballot(bv[j] <= thr);
    while (msk) {  // ascending block order; wave-uniform control
      const int b = j * 64 + (__ffsll((long long)msk) - 1);
      msk &= msk - 1;
      const int s0 = b * SBLK + lane * SPL;
      if (SPL == 2) {
        float a0 = 0.f, a1 = 0.f;
#pragma unroll
        for (int c = 0; c < 16; ++c) {
          const float4 qv = *(const float4*)&sQrow[w][c * 4];
          const float2 x0 = *(const float2*)&S_T[(size_t)(c * 4 + 0) * NTOT + s0];
          const float2 x1 = *(const float2*)&S_T[(size_t)(c * 4 + 1) * NTOT + s0];
          const float2 x2 = *(const float2*)&S_T[(size_t)(c * 4 + 2) * NTOT + s0];
          const float2 x3 = *(const float2*)&S_T[(size_t)(c * 4 + 3) * NTOT + s0];
          a0 = fmaf(qv.x, x0.x, a0); a1 = fmaf(qv.x, x0.y, a1);
          a0 = fmaf(qv.y, x1.x, a0); a1 = fmaf(qv.y, x1.y, a1);
          a0 = fmaf(qv.z, x2.x, a0); a1 = fmaf(qv.z, x2.y, a1);
          a0 = fmaf(qv.w, x3.x, a0); a1 = fmaf(qv.w, x3.y, a1);
        }
        const float2 sq2 = *(const float2*)&sqS[s0];
        const float k0 = fmaf(-2.f, a0, sq2.x);
        const float k1 = fmaf(-2.f, a1, sq2.y);
        bool u;  // ascending index, strict < => first minimum per lane
        u = k0 < bk; bk = u ? k0 : bk; bi = u ? s0 : bi;
        u = k1 < bk; bk = u ? k1 : bk; bi = u ? (s0 + 1) : bi;
      } else {
        float a0 = 0.f, a1 = 0.f, a2 = 0.f, a3 = 0.f;
#pragma unroll
        for (int c = 0; c < 16; ++c) {
          const float4 qv = *(const float4*)&sQrow[w][c * 4];
          const float4 s0v = *(const float4*)&S_T[(size_t)(c * 4 + 0) * NTOT + s0];
          const float4 s1v = *(const float4*)&S_T[(size_t)(c * 4 + 1) * NTOT + s0];
          const float4 s2v = *(const float4*)&S_T[(size_t)(c * 4 + 2) * NTOT + s0];
          const float4 s3v = *(const float4*)&S_T[(size_t)(c * 4 + 3) * NTOT + s0];
          a0 = fmaf(qv.x, s0v.x, a0); a1 = fmaf(qv.x, s0v.y, a1);
          a2 = fmaf(qv.x, s0v.z, a2); a3 = fmaf(qv.x, s0v.w, a3);
          a0 = fmaf(qv.y, s1v.x, a0); a1 = fmaf(qv.y, s1v.y, a1);
          a2 = fmaf(qv.y, s1v.z, a2); a3 = fmaf(qv.y, s1v.w, a3);
          a0 = fmaf(qv.z, s2v.x, a0); a1 = fmaf(qv.z, s2v.y, a1);
          a2 = fmaf(qv.z, s2v.z, a2); a3 = fmaf(qv.z, s2v.w, a3);
          a0 = fmaf(qv.w, s3v.x, a0); a1 = fmaf(qv.w, s3v.y, a1);
          a2 = fmaf(qv.w, s3v.z, a2); a3 = fmaf(qv.w, s3v.w, a3);
        }
        const float4 sq4 = *(const float4*)&sqS[s0];
        const float k0 = fmaf(-2.f, a0, sq4.x);
        const float k1 = fmaf(-2.f, a1, sq4.y);
        const float k2 = fmaf(-2.f, a2, sq4.z);
        const float k3 = fmaf(-2.f, a3, sq4.w);
        bool u;
        u = k0 < bk; bk = u ? k0 : bk; bi = u ? s0 : bi;
        u = k1 < bk; bk = u ? k1 : bk; bi = u ? (s0 + 1) : bi;
        u = k2 < bk; bk = u ? k2 : bk; bi = u ? (s0 + 2) : bi;
        u = k3 < bk; bk = u ? k3 : bk; bi = u ? (s0 + 3) : bi;
      }
    }
  }
  // Cross-lane lexicographic argmin on exact keys => first-index semantics.
#pragma unroll
  for (int d = 1; d < 64; d <<= 1) {
    const float ok = __shfl_xor(bk, d, 64);
    const int oi = __shfl_xor(bi, d, 64);
    const bool u = (ok < bk) || (ok == bk && oi < bi);
    bk = u ? ok : bk;
    bi = u ? oi : bi;
  }
  // Label: one-hot rows exact {0,1}; first 1 == np.argmax.
  const float ov = onehot[(size_t)bi * 64 + lane];
  const unsigned long long lmask = __ballot(ov > 0.5f);
  const int label = __ffsll((long long)lmask) - 1;
  out[(size_t)q * 64 + lane] = (lane == label) ? 1.0f : 0.0f;
}

// ---------------------------------------------------------------------------
extern "C" void kernel_launch(void* const* d_in, const int* in_sizes, int n_in,
                              void* d_out, int out_size, void* d_ws, size_t ws_size,
                              hipStream_t stream) {
  const float* S = (const float*)d_in[0];   // [16384][64]
  const float* Q = (const float*)d_in[1];   // [16384][64]
  const float* OH = (const float*)d_in[2];  // [16384][64]
  float* out = (float*)d_out;

  char* ws = (char*)d_ws;
  ushort* Sh = (ushort*)ws;                                  // [0, 2MB)
  ushort* Qh = (ushort*)(ws + (2u << 20));                   // [2, 4MB)
  float* S_T = (float*)(ws + (4u << 20));                    // [4, 8MB)
  float* sqS = (float*)(ws + (8u << 20));                    // 64 KB
  float* sqQ = (float*)(ws + (8u << 20) + (64u << 10));      // 64 KB
  float* bmin = (float*)(ws + (8u << 20) + (128u << 10));    // up to 8 MB

  k_prep<<<dim3(512), 256, 0, stream>>>(S, Q, Sh, Qh, sqS, sqQ, S_T);

  if (ws_size >= (17u << 20)) {
    k_phaseA<8><<<dim3(8, NTOT / 64), 256, 0, stream>>>(Sh, Qh, sqS, bmin);
    k_phaseB<128><<<dim3(NTOT / 4), 256, 0, stream>>>(S_T, Q, sqS, sqQ,
                                                      bmin, OH, out);
  } else {
    k_phaseA<16><<<dim3(8, NTOT / 64), 256, 0, stream>>>(Sh, Qh, sqS, bmin);
    k_phaseB<256><<<dim3(NTOT / 4), 256, 0, stream>>>(S_T, Q, sqS, sqQ,
                                                      bmin, OH, out);
  }
  (void)in_sizes; (void)n_in; (void)out_size; (void)ws_size;
}